// Round 15
// baseline (3812.996 us; speedup 1.0000x reference)
//
#include <hip/hip_runtime.h>
#include <cstdint>
#include <cstddef>

#define T_STEPS 2048
#define BATCH 64

typedef _Float16 f16;
typedef _Float16 f16x2 __attribute__((ext_vector_type(2)));
typedef _Float16 f16x8 __attribute__((ext_vector_type(8)));
typedef float f32x4 __attribute__((ext_vector_type(4)));
typedef unsigned int uint32;
typedef unsigned long long uint64;
typedef uint32 u32x4 __attribute__((ext_vector_type(4)));

__device__ __forceinline__ float dot2(uint32 w, uint32 h, float c) {
  f16x2 a = __builtin_bit_cast(f16x2, w);
  f16x2 b = __builtin_bit_cast(f16x2, h);
  return __builtin_amdgcn_fdot2(a, b, c, false);
}

__device__ __forceinline__ float dot8(u32x4 w, u32x4 h, float c) {
  c = dot2(w[0], h[0], c);
  c = dot2(w[1], h[1], c);
  c = dot2(w[2], h[2], c);
  c = dot2(w[3], h[3], c);
  return c;
}

__device__ __forceinline__ uint32 pack2(f16 a, f16 b) {
  f16x2 t; t[0] = a; t[1] = b;
  return __builtin_bit_cast(uint32, t);
}

// ---------------------------------------------------------------- setup ----
// whp layout: [kq 0..31][out 0..1023][c 0..3] u32 (f16 pair) -- thread with
// output o reads whp[kq*4096 + o*4 ..] as one coalesced dwordx4.
__global__ __launch_bounds__(256) void setup_weights(
    const float* __restrict__ Wf, const float* __restrict__ Wi,
    const float* __restrict__ Wo, const float* __restrict__ Wc,
    const float* __restrict__ Wout,
    f16* __restrict__ wx16, f16* __restrict__ wout16, uint32* __restrict__ whp)
{
  int id = blockIdx.x * 256 + threadIdx.x;
  const float* WG_[4] = {Wf, Wi, Wo, Wc};
  if (id < 262144) {                       // WxAll f16 [1024][256] (x-part cols)
    int n = id >> 8, k = id & 255;
    int G = n >> 8, j = n & 255;
    wx16[id] = (f16)WG_[G][j * 512 + k];
    return;
  }
  id -= 262144;
  if (id < 65536) { wout16[id] = (f16)Wout[id]; return; }   // Wout f16 [256][256]
  id -= 65536;
  if (id < 131072) {                       // whp: packed f16 h-weights
    int kq = id >> 12, rem = id & 4095;
    int o = rem >> 2, c = rem & 3;
    int G = o >> 8, j = o & 255;
    const float* src = WG_[G] + j * 512 + 256 + kq * 8 + c * 2;
    whp[id] = pack2((f16)src[0], (f16)src[1]);
  }
}

// hbuf: [parity 2][slot 256 = r*4+q][32 u64]; each u64 = 2 tagged u32
// ((tag<<16)|f16). parity0 = tag0|h0 ; parity1 = sentinel 0xFFFF tags.
__global__ __launch_bounds__(256) void setup_state(
    const float* __restrict__ h0, const float* __restrict__ C0,
    uint64* __restrict__ hbuf, float* __restrict__ c32)
{
  int id = blockIdx.x * 256 + threadIdx.x;
  if (id < 8192) {
    int slot = id >> 5, i = id & 31;
    int r = slot >> 2, q = slot & 3;
    const float* hr = h0 + r * 256 + q * 64 + 2 * i;
    uint32 a = (uint32)__builtin_bit_cast(unsigned short, (f16)hr[0]);
    uint32 b = (uint32)__builtin_bit_cast(unsigned short, (f16)hr[1]);
    hbuf[id] = ((uint64)b << 32) | (uint64)a;
    return;
  }
  id -= 8192;
  if (id < 8192) { hbuf[8192 + id] = 0xFFFF0000FFFF0000ULL; return; }
  id -= 8192;
  if (id < 16384) c32[id] = C0[id];
}

// ---------------------------------------------------------------- GEMM -----
template<int A_F32, int OUT_F32_BIAS>
__global__ __launch_bounds__(256) void gemm_k(
    const void* __restrict__ Av, const f16* __restrict__ B,
    void* __restrict__ Cv, const float* __restrict__ bias, int N)
{
  constexpr int LDA = 264;
  __shared__ f16 As[128 * 264];
  __shared__ f16 Bs[128 * 264];
  const int tid = threadIdx.x;
  const int m0 = blockIdx.x * 128;
  const int n0 = blockIdx.y * 128;

  if (A_F32) {
    const float* A = (const float*)Av;
    #pragma unroll
    for (int j = 0; j < 32; ++j) {
      int flat = (tid + j * 256) * 4;
      int row = flat >> 8, col = flat & 255;
      const float4 v = *(const float4*)(A + (size_t)(m0 + row) * 256 + col);
      uint2 u; u.x = pack2((f16)v.x, (f16)v.y); u.y = pack2((f16)v.z, (f16)v.w);
      *(uint2*)&As[row * LDA + col] = u;
    }
  } else {
    const f16* A = (const f16*)Av;
    #pragma unroll
    for (int j = 0; j < 32; ++j) {
      int flat = (tid + j * 256) * 4;
      int row = flat >> 8, col = flat & 255;
      *(uint2*)&As[row * LDA + col] = *(const uint2*)(A + (size_t)(m0 + row) * 256 + col);
    }
  }
  #pragma unroll
  for (int j = 0; j < 32; ++j) {
    int flat = (tid + j * 256) * 4;
    int row = flat >> 8, col = flat & 255;
    *(uint2*)&Bs[row * LDA + col] = *(const uint2*)(B + (size_t)(n0 + row) * 256 + col);
  }
  __syncthreads();

  const int wave = tid >> 6, l = tid & 63;
  const int wr = wave >> 1, wc = wave & 1;
  const int lr = l & 15, lq = l >> 4;

  f32x4 acc[4][4] = {};
  #pragma unroll
  for (int kk = 0; kk < 8; ++kk) {
    f16x8 a[4], b[4];
    #pragma unroll
    for (int mi = 0; mi < 4; ++mi)
      a[mi] = *(const f16x8*)&As[(64 * wr + 16 * mi + lr) * LDA + kk * 32 + lq * 8];
    #pragma unroll
    for (int ni = 0; ni < 4; ++ni)
      b[ni] = *(const f16x8*)&Bs[(64 * wc + 16 * ni + lr) * LDA + kk * 32 + lq * 8];
    #pragma unroll
    for (int mi = 0; mi < 4; ++mi)
      #pragma unroll
      for (int ni = 0; ni < 4; ++ni)
        acc[mi][ni] = __builtin_amdgcn_mfma_f32_16x16x32_f16(a[mi], b[ni], acc[mi][ni], 0, 0, 0);
  }

  #pragma unroll
  for (int mi = 0; mi < 4; ++mi) {
    #pragma unroll
    for (int ni = 0; ni < 4; ++ni) {
      int col = n0 + 64 * wc + 16 * ni + lr;
      float bv = 0.f;
      if (OUT_F32_BIAS) bv = bias[col];
      #pragma unroll
      for (int v = 0; v < 4; ++v) {
        int row = m0 + 64 * wr + 16 * mi + lq * 4 + v;
        if (OUT_F32_BIAS) ((float*)Cv)[(size_t)row * N + col] = acc[mi][ni][v] + bv;
        else              ((f16*)Cv)[(size_t)row * N + col] = (f16)acc[mi][ni][v];
      }
    }
  }
}

// --------------------------------------------------------- persistent LSTM -
// R15: quarter-row split. 256 WGs x 256 thr; WG (r = w&63, q = w>>6) owns
// 4 gates x columns [64q, 64q+64) of row r, full K=256 per thread (G=tid>>6,
// col=tid&63). Weights: 20 named-reg quads (80 VGPR -- safe under either
// observed allocator budget) + 12 LDS quads (48KB). All 256 CUs active,
// per-WG step work halved vs R14.
// Exchange = R14's replay-proven skeleton verbatim, degree 3: spin-at-top
// (tag gt, parity gt&1), tl==0 own-quarter path, pointwise -> hstage,
// publish-from-hstage fire-and-forget tagged u64 atomics (tag rides in
// data), parity ping-pong. Same inductive overwrite-safety: publishing
// tag t+1 requires having consumed ALL siblings' tag t, which implies each
// sibling finished reading tag t-1 from the buffer being overwritten.
// Quarters of row r are blockIdx r, r+64, r+128, r+192 == r (mod 8): same
// XCD under round-robin; correctness placement-independent.
#define RL20(M) M(0) M(1) M(2) M(3) M(4) M(5) M(6) M(7) M(8) M(9) M(10) M(11) \
  M(12) M(13) M(14) M(15) M(16) M(17) M(18) M(19)

__global__ __launch_bounds__(256) void lstm_persist(
    const uint32* __restrict__ whp,
    const float* __restrict__ bf, const float* __restrict__ bi,
    const float* __restrict__ bo, const float* __restrict__ bc,
    const f16* __restrict__ xproj, uint64* __restrict__ hbuf,
    float* __restrict__ c32, float* __restrict__ hid_out,
    f16* __restrict__ h16c, float* __restrict__ cf_out, int t0, int Tc)
{
  __shared__ u32x4 wlds[12 * 256];                           // 48KB LDS quads
  __shared__ uint32 h_lds[128] __attribute__((aligned(16))); // full h (256 f16)
  __shared__ float part[4 * 68];                             // padded pre-acts
  __shared__ unsigned short hstage[64];                      // new own-quarter h

  const int tid = threadIdx.x;
  const int w = blockIdx.x;
  const int q = w >> 6, r = w & 63;
  const int G = tid >> 6, col = tid & 63;
  const int j = q * 64 + col;                  // global column
  const int o = (G << 8) + j;                  // whp output index

  const u32x4* wq = (const u32x4*)whp;         // [kq*1024 + o]

  // ---- one-time: kq 0..19 named regs, kq 20..31 into LDS ----
#define LOADW(i) u32x4 w##i = wq[(i) * 1024 + o];
  RL20(LOADW)
#undef LOADW
  #pragma unroll
  for (int i = 0; i < 12; ++i)
    wlds[i * 256 + tid] = wq[(20 + i) * 1024 + o];

  const float* bGp = (G == 0) ? bf : (G == 1) ? bi : (G == 2) ? bo : bc;
  const float biasv = bGp[j];

  float Creg = 0.f;
  if (tid < 64) Creg = c32[r * 256 + q * 64 + tid];

  uint64* mybuf = hbuf + (size_t)(r * 4 + q) * 32;   // + parity*8192

  for (int tl = 0; tl < Tc; ++tl) {
    const int gt = t0 + tl;
    const int pp = gt & 1;

    // A: x-projection load (hides under the spin)
    const float xpv = (float)xproj[((size_t)tl * 64 + r) * 1024 + o];

    // B: fill h_lds. Sibling quarters (3x32 u64): tag-validated spin, tid<96.
    // Own quarter: maintained by phase H, except tl==0 (tid 96..127 load it).
    if (tid < 96) {
      const int s = tid >> 5, i = tid & 31;
      const int qq = s + (s >= q ? 1 : 0);
      const uint64* p = hbuf + (size_t)pp * 8192 + (size_t)(r * 4 + qq) * 32 + i;
      const uint32 tg = (uint32)gt;
      uint64 v = __hip_atomic_load(p, __ATOMIC_RELAXED, __HIP_MEMORY_SCOPE_AGENT);
      int tries = 0;
      while (((((uint32)v) >> 16) != tg || ((uint32)(v >> 48)) != tg) &&
             ++tries < (1 << 20)) {
        v = __hip_atomic_load(p, __ATOMIC_RELAXED, __HIP_MEMORY_SCOPE_AGENT);
      }
      h_lds[qq * 32 + i] =
          (((uint32)v) & 0xFFFFu) | ((((uint32)(v >> 32)) & 0xFFFFu) << 16);
    } else if (tl == 0 && tid < 128) {
      const int i = tid - 96;
      const uint64* p = mybuf + (size_t)pp * 8192 + i;
      const uint32 tg = (uint32)gt;
      uint64 v = __hip_atomic_load(p, __ATOMIC_RELAXED, __HIP_MEMORY_SCOPE_AGENT);
      int tries = 0;
      while (((((uint32)v) >> 16) != tg || ((uint32)(v >> 48)) != tg) &&
             ++tries < (1 << 20)) {
        v = __hip_atomic_load(p, __ATOMIC_RELAXED, __HIP_MEMORY_SCOPE_AGENT);
      }
      h_lds[q * 32 + i] =
          (((uint32)v) & 0xFFFFu) | ((((uint32)(v >> 32)) & 0xFFFFu) << 16);
    }
    __syncthreads();  // C

    // D: full-K dot chain (20 reg quads + 12 LDS quads, 4-way acc split)
    int otid;
    asm volatile("v_mov_b32 %0, %1" : "=v"(otid) : "v"(tid));
    float ac[4] = {0.f, 0.f, 0.f, 0.f};
#define DOTW(i) { const u32x4 hh = *(const u32x4*)&h_lds[(i) * 4]; \
                  ac[(i) & 3] = dot8(w##i, hh, ac[(i) & 3]); }
    RL20(DOTW)
#undef DOTW
    #pragma unroll
    for (int i = 0; i < 12; ++i) {
      const u32x4 hh = *(const u32x4*)&h_lds[(20 + i) * 4];
      ac[(20 + i) & 3] = dot8(wlds[i * 256 + otid], hh, ac[(20 + i) & 3]);
    }
    part[G * 68 + col] = (ac[0] + ac[1]) + (ac[2] + ac[3]) + xpv + biasv;
    __syncthreads();  // E

    // F: pointwise update (tid<64 owns column j = q*64+tid) -> hstage
    if (tid < 64) {
      const float pf = part[tid];
      const float pi = part[68 + tid];
      const float po = part[136 + tid];
      const float pc = part[204 + tid];
      const float f_ = __builtin_amdgcn_rcpf(1.f + __expf(-pf));
      const float i_ = __builtin_amdgcn_rcpf(1.f + __expf(-pi));
      const float o_ = __builtin_amdgcn_rcpf(1.f + __expf(-po));
      const float cb = 1.f - 2.f * __builtin_amdgcn_rcpf(__expf(2.f * pc) + 1.f);
      const float Cn = f_ * Creg + i_ * cb;
      Creg = Cn;
      const float th = 1.f - 2.f * __builtin_amdgcn_rcpf(__expf(2.f * Cn) + 1.f);
      const float hn = o_ * th;
      const int jg = q * 64 + tid;
      hid_out[((size_t)gt * 64 + r) * 256 + jg] = hn;
      const f16 h16v = (f16)hn;
      hstage[tid] = __builtin_bit_cast(unsigned short, h16v);
      h16c[((size_t)tl * 64 + r) * 256 + jg] = h16v;
      if (gt == T_STEPS - 1) cf_out[r * 256 + jg] = Cn;
    }
    __syncthreads();  // G

    // H: publish own quarter (fire-and-forget tagged u64 atomics) + local
    // h_lds own-quarter update for the next step's dots.
    if (tid < 32) {
      const uint32 a = (uint32)hstage[2 * tid];
      const uint32 b = (uint32)hstage[2 * tid + 1];
      h_lds[q * 32 + tid] = a | (b << 16);
      const uint32 tg1u = ((uint32)(gt + 1)) << 16;
      const uint64 v = ((uint64)(b | tg1u) << 32) | (uint64)(a | tg1u);
      __hip_atomic_store(mybuf + (size_t)((gt + 1) & 1) * 8192 + tid, v,
                         __ATOMIC_RELAXED, __HIP_MEMORY_SCOPE_AGENT);
    }
  }

  if (tid < 64) c32[r * 256 + q * 64 + tid] = Creg;
}

// ---------------------------------------------------------------- host -----
extern "C" void kernel_launch(void* const* d_in, const int* in_sizes, int n_in,
                              void* d_out, int out_size, void* d_ws, size_t ws_size,
                              hipStream_t stream)
{
  const float* x    = (const float*)d_in[0];
  const float* h0   = (const float*)d_in[1];
  const float* C0   = (const float*)d_in[2];
  const float* Wf   = (const float*)d_in[3];
  const float* bf   = (const float*)d_in[4];
  const float* Wi   = (const float*)d_in[5];
  const float* bi   = (const float*)d_in[6];
  const float* Wo   = (const float*)d_in[7];
  const float* bo   = (const float*)d_in[8];
  const float* Wc   = (const float*)d_in[9];
  const float* bc   = (const float*)d_in[10];
  const float* Wout = (const float*)d_in[11];
  const float* bout = (const float*)d_in[12];
  float* out = (float*)d_out;

  char* w = (char*)d_ws;
  f16*    wx16   = (f16*)w;    w += (size_t)1024 * 256 * 2;
  f16*    wout16 = (f16*)w;    w += (size_t)256 * 256 * 2;
  uint32* whp    = (uint32*)w; w += (size_t)131072 * 4;
  uint64* hbuf   = (uint64*)w; w += (size_t)2 * 8192 * 8;
  float*  c32    = (float*)w;  w += (size_t)64 * 256 * 4;
  const size_t fixedB = (size_t)(w - (char*)d_ws);

  int Tc = 2;
  const int cands[] = {2048, 1024, 512, 256, 128, 64, 32, 16, 8, 4, 2};
  for (int c : cands) {
    if (fixedB + (size_t)c * 163840 <= ws_size) { Tc = c; break; }
  }

  f16* xproj = (f16*)w;
  f16* h16c  = (f16*)(w + (size_t)Tc * 64 * 1024 * 2);

  setup_weights<<<1792, 256, 0, stream>>>(Wf, Wi, Wo, Wc, Wout,
                                          wx16, wout16, whp);
  setup_state<<<128, 256, 0, stream>>>(h0, C0, hbuf, c32);

  float* hid_out = out + (size_t)T_STEPS * 64 * 256;
  float* cf_out  = out + (size_t)2 * T_STEPS * 64 * 256;

  for (int t0 = 0; t0 < T_STEPS; t0 += Tc) {
    gemm_k<1, 0><<<dim3(Tc * 64 / 128, 8), 256, 0, stream>>>(
        x + (size_t)t0 * 64 * 256, wx16, xproj, nullptr, 1024);
    lstm_persist<<<256, 256, 0, stream>>>(whp, bf, bi, bo, bc,
                                          xproj, hbuf, c32,
                                          hid_out, h16c, cf_out, t0, Tc);
    gemm_k<0, 1><<<dim3(Tc * 64 / 128, 2), 256, 0, stream>>>(
        h16c, wout16, out + (size_t)t0 * 64 * 256, bout, 256);
  }
}

// Round 17
// 3376.408 us; speedup vs baseline: 1.1293x; 1.1293x over previous
//
#include <hip/hip_runtime.h>
#include <cstdint>
#include <cstddef>

#define T_STEPS 2048
#define BATCH 64

typedef _Float16 f16;
typedef _Float16 f16x2 __attribute__((ext_vector_type(2)));
typedef _Float16 f16x8 __attribute__((ext_vector_type(8)));
typedef float f32x4 __attribute__((ext_vector_type(4)));
typedef unsigned int uint32;
typedef unsigned long long uint64;
typedef uint32 u32x4 __attribute__((ext_vector_type(4)));

__device__ __forceinline__ float dot2(uint32 w, uint32 h, float c) {
  f16x2 a = __builtin_bit_cast(f16x2, w);
  f16x2 b = __builtin_bit_cast(f16x2, h);
  return __builtin_amdgcn_fdot2(a, b, c, false);
}

__device__ __forceinline__ float dot8(u32x4 w, u32x4 h, float c) {
  c = dot2(w[0], h[0], c);
  c = dot2(w[1], h[1], c);
  c = dot2(w[2], h[2], c);
  c = dot2(w[3], h[3], c);
  return c;
}

__device__ __forceinline__ uint32 pack2(f16 a, f16 b) {
  f16x2 t; t[0] = a; t[1] = b;
  return __builtin_bit_cast(uint32, t);
}

// ---------------------------------------------------------------- setup ----
// whp layout: [kq 0..31][out 0..1023][c 0..3] u32 (f16 pair) -- thread with
// output o reads whp[kq*4096 + o*4 ..] as one coalesced dwordx4.
__global__ __launch_bounds__(256) void setup_weights(
    const float* __restrict__ Wf, const float* __restrict__ Wi,
    const float* __restrict__ Wo, const float* __restrict__ Wc,
    const float* __restrict__ Wout,
    f16* __restrict__ wx16, f16* __restrict__ wout16, uint32* __restrict__ whp)
{
  int id = blockIdx.x * 256 + threadIdx.x;
  const float* WG_[4] = {Wf, Wi, Wo, Wc};
  if (id < 262144) {                       // WxAll f16 [1024][256] (x-part cols)
    int n = id >> 8, k = id & 255;
    int G = n >> 8, j = n & 255;
    wx16[id] = (f16)WG_[G][j * 512 + k];
    return;
  }
  id -= 262144;
  if (id < 65536) { wout16[id] = (f16)Wout[id]; return; }   // Wout f16 [256][256]
  id -= 65536;
  if (id < 131072) {                       // whp: packed f16 h-weights
    int kq = id >> 12, rem = id & 4095;
    int o = rem >> 2, c = rem & 3;
    int G = o >> 8, j = o & 255;
    const float* src = WG_[G] + j * 512 + 256 + kq * 8 + c * 2;
    whp[id] = pack2((f16)src[0], (f16)src[1]);
  }
}

// hbuf: [parity 2][slot 128 = r*2+hf][64 u64]; each u64 = 2 tagged u32
// ((tag<<16)|f16). parity0 = tag0|h0 ; parity1 = sentinel 0xFFFF tags.
__global__ __launch_bounds__(256) void setup_state(
    const float* __restrict__ h0, const float* __restrict__ C0,
    uint64* __restrict__ hbuf, float* __restrict__ c32)
{
  int id = blockIdx.x * 256 + threadIdx.x;
  if (id < 8192) {
    int slot = id >> 6, i = id & 63;
    int r = slot >> 1, hf = slot & 1;
    const float* hr = h0 + r * 256 + hf * 128 + 2 * i;
    uint32 a = (uint32)__builtin_bit_cast(unsigned short, (f16)hr[0]);
    uint32 b = (uint32)__builtin_bit_cast(unsigned short, (f16)hr[1]);
    hbuf[id] = ((uint64)b << 32) | (uint64)a;
    return;
  }
  id -= 8192;
  if (id < 8192) { hbuf[8192 + id] = 0xFFFF0000FFFF0000ULL; return; }
  id -= 8192;
  if (id < 16384) c32[id] = C0[id];
}

// ---------------------------------------------------------------- GEMM -----
template<int A_F32, int OUT_F32_BIAS>
__global__ __launch_bounds__(256) void gemm_k(
    const void* __restrict__ Av, const f16* __restrict__ B,
    void* __restrict__ Cv, const float* __restrict__ bias, int N)
{
  constexpr int LDA = 264;
  __shared__ f16 As[128 * 264];
  __shared__ f16 Bs[128 * 264];
  const int tid = threadIdx.x;
  const int m0 = blockIdx.x * 128;
  const int n0 = blockIdx.y * 128;

  if (A_F32) {
    const float* A = (const float*)Av;
    #pragma unroll
    for (int j = 0; j < 32; ++j) {
      int flat = (tid + j * 256) * 4;
      int row = flat >> 8, col = flat & 255;
      const float4 v = *(const float4*)(A + (size_t)(m0 + row) * 256 + col);
      uint2 u; u.x = pack2((f16)v.x, (f16)v.y); u.y = pack2((f16)v.z, (f16)v.w);
      *(uint2*)&As[row * LDA + col] = u;
    }
  } else {
    const f16* A = (const f16*)Av;
    #pragma unroll
    for (int j = 0; j < 32; ++j) {
      int flat = (tid + j * 256) * 4;
      int row = flat >> 8, col = flat & 255;
      *(uint2*)&As[row * LDA + col] = *(const uint2*)(A + (size_t)(m0 + row) * 256 + col);
    }
  }
  #pragma unroll
  for (int j = 0; j < 32; ++j) {
    int flat = (tid + j * 256) * 4;
    int row = flat >> 8, col = flat & 255;
    *(uint2*)&Bs[row * LDA + col] = *(const uint2*)(B + (size_t)(n0 + row) * 256 + col);
  }
  __syncthreads();

  const int wave = tid >> 6, l = tid & 63;
  const int wr = wave >> 1, wc = wave & 1;
  const int lr = l & 15, lq = l >> 4;

  f32x4 acc[4][4] = {};
  #pragma unroll
  for (int kk = 0; kk < 8; ++kk) {
    f16x8 a[4], b[4];
    #pragma unroll
    for (int mi = 0; mi < 4; ++mi)
      a[mi] = *(const f16x8*)&As[(64 * wr + 16 * mi + lr) * LDA + kk * 32 + lq * 8];
    #pragma unroll
    for (int ni = 0; ni < 4; ++ni)
      b[ni] = *(const f16x8*)&Bs[(64 * wc + 16 * ni + lr) * LDA + kk * 32 + lq * 8];
    #pragma unroll
    for (int mi = 0; mi < 4; ++mi)
      #pragma unroll
      for (int ni = 0; ni < 4; ++ni)
        acc[mi][ni] = __builtin_amdgcn_mfma_f32_16x16x32_f16(a[mi], b[ni], acc[mi][ni], 0, 0, 0);
  }

  #pragma unroll
  for (int mi = 0; mi < 4; ++mi) {
    #pragma unroll
    for (int ni = 0; ni < 4; ++ni) {
      int col = n0 + 64 * wc + 16 * ni + lr;
      float bv = 0.f;
      if (OUT_F32_BIAS) bv = bias[col];
      #pragma unroll
      for (int v = 0; v < 4; ++v) {
        int row = m0 + 64 * wr + 16 * mi + lq * 4 + v;
        if (OUT_F32_BIAS) ((float*)Cv)[(size_t)row * N + col] = acc[mi][ni][v] + bv;
        else              ((f16*)Cv)[(size_t)row * N + col] = (f16)acc[mi][ni][v];
      }
    }
  }
}

// --------------------------------------------------------- persistent LSTM -
// R17 = R14's replay-proven exchange primitives + wave-local epilogue +
// correctly-fenced flight overlap (R13's race fixed by barrier B2).
// 128 WGs x 512 thr; WG = (row r, half hf). 8 waves; wave wv owns columns
// [hf*128+16wv, +16) x 4 gates; lane l: gate g=l>>4, col cl=l&15.
// Weights: 16 own-half + 4 sibling quads in named VGPRs + 12 sibling quads
// in 96KB LDS (full residency). Per step:
//   phase1 own-half dots (overlaps sibling publish flight)
//   phase2 spin sibling half (tagged u64 relaxed-agent atomics) ; B1
//   phase3 sibling dots ; phase4 shfl gate-gather + pointwise (all lanes,
//   redundant-deterministic) + publish straight from waves ; B2.
// No part[] array, 2 barriers/step (R14: 3 + LDS round-trip).
#define RLO16(M) M(0) M(1) M(2) M(3) M(4) M(5) M(6) M(7) M(8) M(9) M(10) M(11) \
  M(12) M(13) M(14) M(15)
#define RLS4(M) M(0) M(1) M(2) M(3)

__global__ __launch_bounds__(512) void lstm_persist(
    const uint32* __restrict__ whp,
    const float* __restrict__ bf, const float* __restrict__ bi,
    const float* __restrict__ bo, const float* __restrict__ bc,
    const f16* __restrict__ xproj, uint64* __restrict__ hbuf,
    float* __restrict__ c32, float* __restrict__ hid_out,
    f16* __restrict__ h16c, float* __restrict__ cf_out, int t0, int Tc)
{
  __shared__ u32x4 wlds[12 * 512];                           // 96KB LDS quads
  __shared__ uint32 h_lds[128] __attribute__((aligned(16))); // full h (256 f16)

  const int tid = threadIdx.x;
  const int w = blockIdx.x;
  const int hf  = (w >> 3) & 1;                // sibling = w ^ 8 (same XCD)
  const int r   = (w & 7) | ((w >> 4) << 3);   // r in [0,64)
  const int wv = tid >> 6, l = tid & 63;
  const int g = l >> 4, cl = l & 15;
  const int j = hf * 128 + 16 * wv + cl;       // this lane's column
  const int o = (g << 8) + j;                  // whp output index

  const int hfo = hf * 64;                     // own-half h_lds base (u32)
  const int sfo = (hf ^ 1) * 64;               // sibling-half base
  const int okq = hf * 16;                     // own-half first K-quad
  const int skq = (hf ^ 1) * 16;               // sibling first K-quad

  const u32x4* wq = (const u32x4*)whp;         // [kq*1024 + o]

  // ---- one-time: 16 own + 4 sib quads in regs, 12 sib quads in LDS ----
#define LOADO(i) u32x4 wo##i = wq[(okq + (i)) * 1024 + o];
  RLO16(LOADO)
#undef LOADO
#define LOADS(i) u32x4 ws##i = wq[(skq + (i)) * 1024 + o];
  RLS4(LOADS)
#undef LOADS
  #pragma unroll
  for (int i = 0; i < 12; ++i)
    wlds[i * 512 + tid] = wq[(skq + 4 + i) * 1024 + o];

  const float* bGp = (g == 0) ? bf : (g == 1) ? bi : (g == 2) ? bo : bc;
  const float biasv = bGp[j];

  float Creg = c32[r * 256 + j];   // all 4 gate-lanes of a column hold it

  uint64* mybuf  = hbuf + (size_t)(r * 2 + hf) * 64;
  uint64* sibbuf = hbuf + (size_t)(r * 2 + (hf ^ 1)) * 64;

  // ---- prologue: own-half h for step t0 (tag-validated, agent scope) ----
  if (tid < 64) {
    const uint64* p = mybuf + (size_t)(t0 & 1) * 8192 + tid;
    const uint32 tg = (uint32)t0;
    uint64 v = __hip_atomic_load(p, __ATOMIC_RELAXED, __HIP_MEMORY_SCOPE_AGENT);
    int tries = 0;
    while (((((uint32)v) >> 16) != tg || ((uint32)(v >> 48)) != tg) &&
           ++tries < (1 << 22)) {
      v = __hip_atomic_load(p, __ATOMIC_RELAXED, __HIP_MEMORY_SCOPE_AGENT);
    }
    h_lds[hfo + tid] =
        (((uint32)v) & 0xFFFFu) | ((((uint32)(v >> 32)) & 0xFFFFu) << 16);
  }
  __syncthreads();

  for (int tl = 0; tl < Tc; ++tl) {
    const int gt = t0 + tl;
    const int pp = gt & 1;

    // x-projection load (hides under phase 1/2)
    const float xpv = (float)xproj[((size_t)tl * 64 + r) * 1024 + o];

    // phase 1: own-half dots (16 reg quads) -- overlaps sibling flight
    float ac0 = 0.f, ac1 = 0.f, ac2 = 0.f, ac3 = 0.f;
#define DOT_O(i) { const u32x4 hh = *(const u32x4*)&h_lds[hfo + (i) * 4]; \
                   float& A_ = (((i) & 3) == 0) ? ac0 : (((i) & 3) == 1) ? ac1 \
                             : (((i) & 3) == 2) ? ac2 : ac3; \
                   A_ = dot8(wo##i, hh, A_); }
    RLO16(DOT_O)
#undef DOT_O

    // phase 2: spin for sibling half (tagged, relaxed-agent; proven)
    if (tid < 64) {
      const uint64* p = sibbuf + (size_t)pp * 8192 + tid;
      const uint32 tg = (uint32)gt;
      uint64 v = __hip_atomic_load(p, __ATOMIC_RELAXED, __HIP_MEMORY_SCOPE_AGENT);
      int tries = 0;
      while (((((uint32)v) >> 16) != tg || ((uint32)(v >> 48)) != tg) &&
             ++tries < (1 << 22)) {
        v = __hip_atomic_load(p, __ATOMIC_RELAXED, __HIP_MEMORY_SCOPE_AGENT);
      }
      h_lds[sfo + tid] =
          (((uint32)v) & 0xFFFFu) | ((((uint32)(v >> 32)) & 0xFFFFu) << 16);
    }
    __syncthreads();  // B1

    // phase 3: sibling-half dots (4 reg + 12 LDS quads)
    int otid;
    asm volatile("v_mov_b32 %0, %1" : "=v"(otid) : "v"(tid));
#define DOT_S(i) { const u32x4 hh = *(const u32x4*)&h_lds[sfo + (i) * 4]; \
                   float& A_ = (((i) & 3) == 0) ? ac0 : (((i) & 3) == 1) ? ac1 \
                             : (((i) & 3) == 2) ? ac2 : ac3; \
                   A_ = dot8(ws##i, hh, A_); }
    RLS4(DOT_S)
#undef DOT_S
    #pragma unroll
    for (int i = 0; i < 12; ++i) {
      const u32x4 hh = *(const u32x4*)&h_lds[sfo + (4 + i) * 4];
      float& A_ = (((4 + i) & 3) == 0) ? ac0 : (((4 + i) & 3) == 1) ? ac1
                : (((4 + i) & 3) == 2) ? ac2 : ac3;
      A_ = dot8(wlds[i * 512 + otid], hh, A_);
    }
    const float acc = (ac0 + ac1) + (ac2 + ac3) + xpv + biasv;

    // phase 4: wave-local gate gather (shfl) + pointwise (all lanes,
    // redundant-deterministic) + publish straight from each wave.
    const float a  = acc;
    const float b  = __shfl_xor(acc, 16, 64);
    const float cx = __shfl_xor(acc, 32, 64);
    const float d  = __shfl_xor(b, 32, 64);
    const float pf = (g == 0) ? a  : (g == 1) ? b  : (g == 2) ? cx : d;
    const float pi = (g == 0) ? b  : (g == 1) ? a  : (g == 2) ? d  : cx;
    const float po = (g == 0) ? cx : (g == 1) ? d  : (g == 2) ? a  : b;
    const float pc = (g == 0) ? d  : (g == 1) ? cx : (g == 2) ? b  : a;

    const float f_ = __builtin_amdgcn_rcpf(1.f + __expf(-pf));
    const float i_ = __builtin_amdgcn_rcpf(1.f + __expf(-pi));
    const float o_ = __builtin_amdgcn_rcpf(1.f + __expf(-po));
    const float cb = 1.f - 2.f * __builtin_amdgcn_rcpf(__expf(2.f * pc) + 1.f);
    const float Cn = f_ * Creg + i_ * cb;
    Creg = Cn;
    const float th = 1.f - 2.f * __builtin_amdgcn_rcpf(__expf(2.f * Cn) + 1.f);
    const float hn = o_ * th;
    const f16 h16v = (f16)hn;

    if (g == 0) {
      hid_out[((size_t)gt * 64 + r) * 256 + j] = hn;
      h16c[((size_t)tl * 64 + r) * 256 + j] = h16v;
      if (gt == T_STEPS - 1) cf_out[r * 256 + j] = Cn;
    }

    const uint32 hb = (uint32)__builtin_bit_cast(unsigned short, h16v);
    const uint32 nb = __shfl_xor((int)hb, 1, 64);
    if (g == 0 && (cl & 1) == 0) {
      const int m = 8 * wv + (cl >> 1);
      h_lds[hfo + m] = hb | (nb << 16);
      const uint32 tg1u = ((uint32)(gt + 1)) << 16;
      const uint64 v = ((uint64)(nb | tg1u) << 32) | (uint64)(hb | tg1u);
      __hip_atomic_store(mybuf + (size_t)((gt + 1) & 1) * 8192 + m, v,
                         __ATOMIC_RELAXED, __HIP_MEMORY_SCOPE_AGENT);
    }
    __syncthreads();  // B2 (protects h_lds[own] for next phase 1 -- R13's bug)
  }

  if (g == 0) c32[r * 256 + j] = Creg;
}

// ---------------------------------------------------------------- host -----
extern "C" void kernel_launch(void* const* d_in, const int* in_sizes, int n_in,
                              void* d_out, int out_size, void* d_ws, size_t ws_size,
                              hipStream_t stream)
{
  const float* x    = (const float*)d_in[0];
  const float* h0   = (const float*)d_in[1];
  const float* C0   = (const float*)d_in[2];
  const float* Wf   = (const float*)d_in[3];
  const float* bf   = (const float*)d_in[4];
  const float* Wi   = (const float*)d_in[5];
  const float* bi   = (const float*)d_in[6];
  const float* Wo   = (const float*)d_in[7];
  const float* bo   = (const float*)d_in[8];
  const float* Wc   = (const float*)d_in[9];
  const float* bc   = (const float*)d_in[10];
  const float* Wout = (const float*)d_in[11];
  const float* bout = (const float*)d_in[12];
  float* out = (float*)d_out;

  char* w = (char*)d_ws;
  f16*    wx16   = (f16*)w;    w += (size_t)1024 * 256 * 2;
  f16*    wout16 = (f16*)w;    w += (size_t)256 * 256 * 2;
  uint32* whp    = (uint32*)w; w += (size_t)131072 * 4;
  uint64* hbuf   = (uint64*)w; w += (size_t)2 * 8192 * 8;
  float*  c32    = (float*)w;  w += (size_t)64 * 256 * 4;
  const size_t fixedB = (size_t)(w - (char*)d_ws);

  int Tc = 2;
  const int cands[] = {2048, 1024, 512, 256, 128, 64, 32, 16, 8, 4, 2};
  for (int c : cands) {
    if (fixedB + (size_t)c * 163840 <= ws_size) { Tc = c; break; }
  }

  f16* xproj = (f16*)w;
  f16* h16c  = (f16*)(w + (size_t)Tc * 64 * 1024 * 2);

  setup_weights<<<1792, 256, 0, stream>>>(Wf, Wi, Wo, Wc, Wout,
                                          wx16, wout16, whp);
  setup_state<<<128, 256, 0, stream>>>(h0, C0, hbuf, c32);

  float* hid_out = out + (size_t)T_STEPS * 64 * 256;
  float* cf_out  = out + (size_t)2 * T_STEPS * 64 * 256;

  for (int t0 = 0; t0 < T_STEPS; t0 += Tc) {
    gemm_k<1, 0><<<dim3(Tc * 64 / 128, 8), 256, 0, stream>>>(
        x + (size_t)t0 * 64 * 256, wx16, xproj, nullptr, 1024);
    lstm_persist<<<128, 512, 0, stream>>>(whp, bf, bi, bo, bc,
                                          xproj, hbuf, c32,
                                          hid_out, h16c, cf_out, t0, Tc);
    gemm_k<0, 1><<<dim3(Tc * 64 / 128, 2), 256, 0, stream>>>(
        h16c, wout16, out + (size_t)t0 * 64 * 256, bout, 256);
  }
}